// Round 2
// baseline (496.832 us; speedup 1.0000x reference)
//
#include <hip/hip_runtime.h>
#include <stdint.h>

// Problem constants
#define BB   8
#define CC   64
#define HH   256
#define WW   256
#define GG   8
#define CPG  8                    // channels per group
#define HWSZ (HH*WW)              // 65536
#define CHW  (CC*HH*WW)           // 4194304
#define GROUPELEMS (CPG*HWSZ)     // 524288
#define EPSV 1e-5f

// ws layout (bytes): tiny — only stats live here. pair array lives in d_out.
#define WS_PART_OFF 0             // 512 x float2  (4 KiB)
#define WS_AFF_OFF  4096          // 512 x float2  (4 KiB)

__device__ __forceinline__ uint32_t f32_to_bf16_bits(float f) {
    uint32_t u = __float_as_uint(f);
    u += 0x7fffu + ((u >> 16) & 1u);   // round-to-nearest-even
    return u >> 16;
}

// ---------------- K1: per-slice partial sums for GroupNorm stats ------------
// grid = B*G*8 = 512 blocks; each block reduces 65536 contiguous floats
// (= 16384 float4, 64 per thread).
__global__ __launch_bounds__(256) void k_stats_partial(
        const float* __restrict__ x, float2* __restrict__ part) {
    int blk = blockIdx.x;                         // ((b*8+g)*8 + s)
    const float4* p = (const float4*)(x + (size_t)blk * 65536);
    int t = threadIdx.x;
    float s = 0.f, s2 = 0.f;
#pragma unroll 8
    for (int i = 0; i < 64; ++i) {                // FIX: was 16 (1/4 coverage)
        float4 v = p[t + i * 256];
        s  += v.x + v.y + v.z + v.w;
        s2 += v.x * v.x + v.y * v.y + v.z * v.z + v.w * v.w;
    }
#pragma unroll
    for (int off = 32; off; off >>= 1) {
        s  += __shfl_down(s,  off, 64);
        s2 += __shfl_down(s2, off, 64);
    }
    __shared__ float2 red[4];
    int wid = t >> 6;
    if ((t & 63) == 0) red[wid] = make_float2(s, s2);
    __syncthreads();
    if (t == 0) {
        float a = 0.f, b2 = 0.f;
#pragma unroll
        for (int i = 0; i < 4; ++i) { a += red[i].x; b2 += red[i].y; }
        part[blk] = make_float2(a, b2);
    }
}

// ---------------- K1b: finalize stats -> per-(b,c) affine (a, bias) --------
__global__ __launch_bounds__(512) void k_stats_final(
        const float2* __restrict__ part,
        const float* __restrict__ gn_w, const float* __restrict__ gn_b,
        float2* __restrict__ aff) {
    __shared__ float2 st[64];
    int t = threadIdx.x;
    if (t < 64) {
        float s = 0.f, s2 = 0.f;
#pragma unroll
        for (int i = 0; i < 8; ++i) { float2 p = part[t * 8 + i]; s += p.x; s2 += p.y; }
        float inv  = 1.0f / (float)GROUPELEMS;
        float mu   = s * inv;
        float var  = s2 * inv - mu * mu;
        float rstd = rsqrtf(var + EPSV);
        st[t] = make_float2(mu, rstd);
    }
    __syncthreads();
    int b = t >> 6, c = t & 63, g = c >> 3;
    float2 mr = st[b * 8 + g];
    float a  = mr.y * gn_w[c];
    float bb = gn_b[c] - mr.x * a;
    aff[t] = make_float2(a, bb);
}

// ---------------- K2: per-row — normalize, 1x1 convs, sigmoid, W-scan ------
// grid = B*H = 2048 blocks of 256. Writes packed (gate_bf16 | hw_bf16<<16)
// into `pair` (which aliases d_out as uint32).
// LDS budget: wg 32768 + hn2 8192 + gv 16640 + affs/bg/bu 1024 = 58624 B
// (< 64 KiB per-workgroup cap — the previous 66816 B silently failed launch).
__global__ __launch_bounds__(256, 2) void k_row(
        const float* __restrict__ x,
        const float* __restrict__ gate_w, const float* __restrict__ gate_b,
        const float* __restrict__ upd_w,  const float* __restrict__ upd_b,
        const float2* __restrict__ aff,
        uint32_t* __restrict__ pair) {
    __shared__ float wg[2][64][64];      // 32 KiB  (gate_w, upd_w)
    __shared__ uint32_t hn2[32][64];     // 8 KiB   normalized tile, bf16 pair (ch 2c2,2c2+1)
    __shared__ uint32_t gv[64][65];      // 16.25 KiB  packed (g,v)/(g,hw) [xi][c]
    __shared__ float2 affs[64];
    __shared__ float bg[64], bu[64];

    int t = threadIdx.x;
    int row = blockIdx.x;
    int b = row >> 8, y = row & 255;

#pragma unroll
    for (int i = 0; i < 16; ++i) {
        int idx = i * 256 + t;           // 0..4095
        ((float*)wg)[idx]        = gate_w[idx];
        ((float*)wg)[4096 + idx] = upd_w[idx];
    }
    if (t < 64) {
        affs[t] = aff[b * 64 + t];
        bg[t] = gate_b[t];
        bu[t] = upd_b[t];
    }
    __syncthreads();

    int wv = t >> 6, lane = t & 63;
    float s_carry = 0.f;                 // W-scan carry (threads 0..63)
    const size_t rowoff = (size_t)b * CHW + (size_t)y * WW;

    for (int tau = 0; tau < 4; ++tau) {
        int x0 = tau * 64;
        // ---- stage normalized x tile into LDS as bf16 pairs ----------------
#pragma unroll
        for (int i = 0; i < 8; ++i) {
            int idx = i * 256 + t;       // 0..2047 (c2, xi)
            int c2 = idx >> 6, xi = idx & 63;
            int c0 = c2 * 2;
            float v0 = x[rowoff + (size_t)c0 * HWSZ + x0 + xi];
            float v1 = x[rowoff + (size_t)(c0 + 1) * HWSZ + x0 + xi];
            float2 ab0 = affs[c0], ab1 = affs[c0 + 1];
            hn2[c2][xi] = f32_to_bf16_bits(v0 * ab0.x + ab0.y)
                        | (f32_to_bf16_bits(v1 * ab1.x + ab1.y) << 16);
        }
        __syncthreads();

        // ---- matvec: each wave owns wave-uniform c_out set {16k+wv+4j} -----
#pragma unroll
        for (int k = 0; k < 4; ++k) {
            int co0 = 16 * k + wv;       // wave-uniform
            int co1 = co0 + 4, co2 = co0 + 8, co3 = co0 + 12;
            float ag0 = bg[co0], ag1 = bg[co1], ag2 = bg[co2], ag3 = bg[co3];
            float au0 = bu[co0], au1 = bu[co1], au2 = bu[co2], au3 = bu[co3];
            const float4* wG0 = (const float4*)&wg[0][co0][0];
            const float4* wG1 = (const float4*)&wg[0][co1][0];
            const float4* wG2 = (const float4*)&wg[0][co2][0];
            const float4* wG3 = (const float4*)&wg[0][co3][0];
            const float4* wU0 = (const float4*)&wg[1][co0][0];
            const float4* wU1 = (const float4*)&wg[1][co1][0];
            const float4* wU2 = (const float4*)&wg[1][co2][0];
            const float4* wU3 = (const float4*)&wg[1][co3][0];
#pragma unroll
            for (int c4 = 0; c4 < 16; ++c4) {
                uint32_t p0 = hn2[c4 * 2 + 0][lane];
                uint32_t p1 = hn2[c4 * 2 + 1][lane];
                float h0 = __uint_as_float(p0 << 16);
                float h1 = __uint_as_float(p0 & 0xffff0000u);
                float h2 = __uint_as_float(p1 << 16);
                float h3 = __uint_as_float(p1 & 0xffff0000u);
                float4 w;
                w = wG0[c4]; ag0 += w.x*h0 + w.y*h1 + w.z*h2 + w.w*h3;
                w = wG1[c4]; ag1 += w.x*h0 + w.y*h1 + w.z*h2 + w.w*h3;
                w = wG2[c4]; ag2 += w.x*h0 + w.y*h1 + w.z*h2 + w.w*h3;
                w = wG3[c4]; ag3 += w.x*h0 + w.y*h1 + w.z*h2 + w.w*h3;
                w = wU0[c4]; au0 += w.x*h0 + w.y*h1 + w.z*h2 + w.w*h3;
                w = wU1[c4]; au1 += w.x*h0 + w.y*h1 + w.z*h2 + w.w*h3;
                w = wU2[c4]; au2 += w.x*h0 + w.y*h1 + w.z*h2 + w.w*h3;
                w = wU3[c4]; au3 += w.x*h0 + w.y*h1 + w.z*h2 + w.w*h3;
            }
            float g0 = 1.f / (1.f + __expf(-ag0));
            float g1 = 1.f / (1.f + __expf(-ag1));
            float g2 = 1.f / (1.f + __expf(-ag2));
            float g3 = 1.f / (1.f + __expf(-ag3));
            gv[lane][co0] = f32_to_bf16_bits(g0) | (f32_to_bf16_bits((1.f - g0) * au0) << 16);
            gv[lane][co1] = f32_to_bf16_bits(g1) | (f32_to_bf16_bits((1.f - g1) * au1) << 16);
            gv[lane][co2] = f32_to_bf16_bits(g2) | (f32_to_bf16_bits((1.f - g2) * au2) << 16);
            gv[lane][co3] = f32_to_bf16_bits(g3) | (f32_to_bf16_bits((1.f - g3) * au3) << 16);
        }
        __syncthreads();

        // ---- W-scan: thread c (<64) serially over 64 xi; replace v by hw ---
        if (t < 64) {
            float s = s_carry;
#pragma unroll 8
            for (int xi = 0; xi < 64; ++xi) {
                uint32_t pk = gv[xi][t];
                float g = __uint_as_float(pk << 16);
                float v = __uint_as_float(pk & 0xffff0000u);
                s = g * s + v;
                gv[xi][t] = (pk & 0xffffu) | (f32_to_bf16_bits(s) << 16);
            }
            s_carry = s;
        }
        __syncthreads();

        // ---- write packed (gate, hw) pairs, coalesced ----------------------
#pragma unroll
        for (int i = 0; i < 16; ++i) {
            int idx = i * 256 + t;
            int c = idx >> 6, xi = idx & 63;
            pair[rowoff + (size_t)c * HWSZ + x0 + xi] = gv[xi][c];
        }
        __syncthreads();   // protect gv/hn2 before next tile's writes
    }
}

// ---------------- K3: H-scan + residual, in-place on d_out -----------------
// grid = B*C = 512 blocks of 256 (thread = xi). io holds packed pairs; each
// element is read then overwritten by the SAME thread -> race-free in place.
__global__ __launch_bounds__(256) void k_hscan(
        uint32_t* io, const float* __restrict__ x) {
    int t = threadIdx.x;
    size_t base = (size_t)blockIdx.x * HWSZ + t;
    float s = 0.f;
    for (int y = 0; y < HH; y += 8) {
        uint32_t pk[8]; float xv[8]; float res[8];
#pragma unroll
        for (int j = 0; j < 8; ++j) pk[j] = io[base + (size_t)(y + j) * WW];
#pragma unroll
        for (int j = 0; j < 8; ++j) xv[j] = x[base + (size_t)(y + j) * WW];
#pragma unroll
        for (int j = 0; j < 8; ++j) {
            float g   = __uint_as_float(pk[j] << 16);
            float hwv = __uint_as_float(pk[j] & 0xffff0000u);
            s = g * s + (1.f - g) * hwv;
            res[j] = xv[j] + s;
        }
#pragma unroll
        for (int j = 0; j < 8; ++j) io[base + (size_t)(y + j) * WW] = __float_as_uint(res[j]);
    }
}

extern "C" void kernel_launch(void* const* d_in, const int* in_sizes, int n_in,
                              void* d_out, int out_size, void* d_ws, size_t ws_size,
                              hipStream_t stream) {
    const float* x      = (const float*)d_in[0];
    const float* gn_w   = (const float*)d_in[1];
    const float* gn_b   = (const float*)d_in[2];
    const float* gate_w = (const float*)d_in[3];
    const float* gate_b = (const float*)d_in[4];
    const float* upd_w  = (const float*)d_in[5];
    const float* upd_b  = (const float*)d_in[6];

    char* ws = (char*)d_ws;
    float2* part = (float2*)(ws + WS_PART_OFF);   // 512 float2
    float2* aff  = (float2*)(ws + WS_AFF_OFF);    // 512 float2
    uint32_t* pair = (uint32_t*)d_out;            // packed (gate,hw), transformed in place by K3

    k_stats_partial<<<512, 256, 0, stream>>>(x, part);
    k_stats_final<<<1, 512, 0, stream>>>(part, gn_w, gn_b, aff);
    k_row<<<BB * HH, 256, 0, stream>>>(x, gate_w, gate_b, upd_w, upd_b, aff, pair);
    k_hscan<<<BB * CC, 256, 0, stream>>>(pair, x);
}

// Round 3
// 447.377 us; speedup vs baseline: 1.1105x; 1.1105x over previous
//
#include <hip/hip_runtime.h>
#include <stdint.h>

// Problem constants
#define BB   8
#define CC   64
#define HH   256
#define WW   256
#define HWSZ (HH*WW)              // 65536
#define CHW  (CC*HH*WW)           // 4194304
#define GROUPELEMS (8*HWSZ)       // 524288 (channels-per-group=8)
#define EPSV 1e-5f

// ws layout (bytes)
#define WS_PART_OFF  0            // 512 x float2   (4 KiB)
#define WS_AFF_OFF   4096         // 512 x float2   (4 KiB)
#define WS_WFRAG_OFF 8192         // 4096 x uint32  (16 KiB)  A-fragment packed weights

typedef __attribute__((ext_vector_type(8))) short bf16x8;
typedef __attribute__((ext_vector_type(4))) float f32x4;
union U32x4 { uint32_t u[4]; uint4 q; bf16x8 v; };

__device__ __forceinline__ uint32_t f32_to_bf16_bits(float f) {
    uint32_t u = __float_as_uint(f);
    u += 0x7fffu + ((u >> 16) & 1u);   // RNE
    return u >> 16;
}

// ---------------- K0: pack fp32 weights into MFMA A-fragment layout --------
// M = 128 (gate rows 0..63, upd rows 64..127), K = 64. 16 frags (8 mt x 2 s),
// lane l holds A[m=16mt+(l&15)][k=32s+8(l>>4)+j], j=0..7 -> 4 dwords.
// wfrag[( (mt*2+s)*64 + l )*4 + d] = bf16pair(k=2d, 2d+1)
__global__ __launch_bounds__(256) void k_wfrag(
        const float* __restrict__ gw, const float* __restrict__ uw,
        uint32_t* __restrict__ wfrag) {
    int idx = blockIdx.x * 256 + threadIdx.x;     // 0..4095
    int fi = idx >> 8, rem = idx & 255;
    int l = rem >> 2, d = rem & 3;
    int mt = fi >> 1, s = fi & 1;
    int m = 16 * mt + (l & 15);
    int k = 32 * s + 8 * (l >> 4) + 2 * d;
    const float* Wr = (m < 64) ? (gw + m * 64) : (uw + (m - 64) * 64);
    wfrag[idx] = f32_to_bf16_bits(Wr[k]) | (f32_to_bf16_bits(Wr[k + 1]) << 16);
}

// ---------------- K1: per-slice partial sums for GroupNorm stats ------------
__global__ __launch_bounds__(256) void k_stats_partial(
        const float* __restrict__ x, float2* __restrict__ part) {
    int blk = blockIdx.x;
    const float4* p = (const float4*)(x + (size_t)blk * 65536);
    int t = threadIdx.x;
    float s = 0.f, s2 = 0.f;
#pragma unroll 16
    for (int i = 0; i < 64; ++i) {
        float4 v = p[t + i * 256];
        s  += v.x + v.y + v.z + v.w;
        s2 += v.x * v.x + v.y * v.y + v.z * v.z + v.w * v.w;
    }
#pragma unroll
    for (int off = 32; off; off >>= 1) {
        s  += __shfl_down(s,  off, 64);
        s2 += __shfl_down(s2, off, 64);
    }
    __shared__ float2 red[4];
    int wid = t >> 6;
    if ((t & 63) == 0) red[wid] = make_float2(s, s2);
    __syncthreads();
    if (t == 0) {
        float a = 0.f, b2 = 0.f;
#pragma unroll
        for (int i = 0; i < 4; ++i) { a += red[i].x; b2 += red[i].y; }
        part[blk] = make_float2(a, b2);
    }
}

// ---------------- K1b: finalize stats -> per-(b,c) affine ------------------
__global__ __launch_bounds__(512) void k_stats_final(
        const float2* __restrict__ part,
        const float* __restrict__ gn_w, const float* __restrict__ gn_b,
        float2* __restrict__ aff) {
    __shared__ float2 st[64];
    int t = threadIdx.x;
    if (t < 64) {
        float s = 0.f, s2 = 0.f;
#pragma unroll
        for (int i = 0; i < 8; ++i) { float2 p = part[t * 8 + i]; s += p.x; s2 += p.y; }
        float inv  = 1.0f / (float)GROUPELEMS;
        float mu   = s * inv;
        float var  = s2 * inv - mu * mu;
        st[t] = make_float2(mu, rsqrtf(var + EPSV));
    }
    __syncthreads();
    int b = t >> 6, c = t & 63, g = c >> 3;
    float2 mr = st[b * 8 + g];
    float a  = mr.y * gn_w[c];
    aff[t] = make_float2(a, gn_b[c] - mr.x * a);
}

// ---------------- K2: MFMA row kernel — norm, convs, sigmoid, W-scan -------
// grid = B*H = 2048 blocks x 256. Two halves of 128 px per row.
// LDS: hn 16896 + gv 33280 + misc 1024 = 51200 B (< 64 KiB cap).
__global__ __launch_bounds__(256) void k_row(
        const float* __restrict__ x,
        const uint32_t* __restrict__ wfrag,
        const float* __restrict__ gate_b, const float* __restrict__ upd_b,
        const float2* __restrict__ aff,
        uint32_t* __restrict__ pair) {
    __shared__ uint32_t hn[128 * 33];   // [px][c-dword], stride 33 dwords (66 bf16)
    __shared__ uint32_t gv[128 * 65];   // [px][c], stride 65 dwords
    __shared__ float2 affs[64];
    __shared__ float bgs[64], bus[64];

    const int t = threadIdx.x;
    const int w = t >> 6, l = t & 63, q = l >> 4, r16 = l & 15;
    const int row = blockIdx.x;
    const int b = row >> 8, y = row & 255;
    const size_t rowoff = (size_t)b * CHW + (size_t)y * WW;

    if (t < 64) { affs[t] = aff[b * 64 + t]; bgs[t] = gate_b[t]; bus[t] = upd_b[t]; }

    // A fragments: 16 coalesced dwordx4 loads
    bf16x8 A[8][2];
#pragma unroll
    for (int mt = 0; mt < 8; ++mt)
#pragma unroll
        for (int s = 0; s < 2; ++s) {
            U32x4 u;
            u.q = *(const uint4*)(wfrag + (((mt << 1) | s) * 64 + l) * 4);
            A[mt][s] = u.v;
        }
    __syncthreads();

    // bias fragments (C/D layout: c = 16mt + 4q + reg)
    float biasG[4][4], biasU[4][4];
#pragma unroll
    for (int mt = 0; mt < 4; ++mt)
#pragma unroll
        for (int r = 0; r < 4; ++r) {
            int c = 16 * mt + 4 * q + r;
            biasG[mt][r] = bgs[c];
            biasU[mt][r] = bus[c];
        }

    float s_carry = 0.f;
    for (int tau = 0; tau < 2; ++tau) {
        const int x0 = tau << 7;
        // ---- stage normalized bf16 tile (writes (px+c)%32 banks: 2-way) ----
#pragma unroll
        for (int i = 0; i < 16; ++i) {
            int idx = i * 256 + t;          // 0..4095
            int c2 = idx >> 7, px = idx & 127;
            int c = c2 << 1;
            float v0 = x[rowoff + (size_t)c * HWSZ + x0 + px];
            float v1 = x[rowoff + (size_t)(c + 1) * HWSZ + x0 + px];
            float2 a0 = affs[c], a1 = affs[c + 1];
            uint32_t lo = f32_to_bf16_bits(v0 * a0.x + a0.y);
            uint32_t hi = f32_to_bf16_bits(v1 * a1.x + a1.y);
            hn[px * 33 + c2] = lo | (hi << 16);
        }
        __syncthreads();

        // ---- MFMA: wave w owns local px [32w, 32w+32) = 2 N-chunks of 16 ---
#pragma unroll
        for (int nc = 0; nc < 2; ++nc) {
            int n_local = (w << 5) + (nc << 4) + r16;
            int based = n_local * 33 + 4 * q;
            U32x4 B0u, B1u;
#pragma unroll
            for (int d = 0; d < 4; ++d) B0u.u[d] = hn[based + d];        // k=8q..8q+7
#pragma unroll
            for (int d = 0; d < 4; ++d) B1u.u[d] = hn[based + 16 + d];   // +32
            f32x4 acc[8];
#pragma unroll
            for (int mt = 0; mt < 4; ++mt) {
                acc[mt]     = f32x4{biasG[mt][0], biasG[mt][1], biasG[mt][2], biasG[mt][3]};
                acc[mt + 4] = f32x4{biasU[mt][0], biasU[mt][1], biasU[mt][2], biasU[mt][3]};
            }
#pragma unroll
            for (int mt = 0; mt < 8; ++mt)
                acc[mt] = __builtin_amdgcn_mfma_f32_16x16x32_bf16(A[mt][0], B0u.v, acc[mt], 0, 0, 0);
#pragma unroll
            for (int mt = 0; mt < 8; ++mt)
                acc[mt] = __builtin_amdgcn_mfma_f32_16x16x32_bf16(A[mt][1], B1u.v, acc[mt], 0, 0, 0);
            // epilogue: sigmoid + pack (g | (1-g)*u<<16) via v_perm
#pragma unroll
            for (int mt = 0; mt < 4; ++mt)
#pragma unroll
                for (int r = 0; r < 4; ++r) {
                    float ga = acc[mt][r];
                    float ua = acc[mt + 4][r];
                    float g  = 1.0f / (1.0f + __expf(-ga));
                    float vv = (1.0f - g) * ua;
                    uint32_t pk = __builtin_amdgcn_perm(__float_as_uint(vv),
                                                        __float_as_uint(g), 0x07060302u);
                    gv[n_local * 65 + 16 * mt + 4 * q + r] = pk;
                }
        }
        __syncthreads();

        // ---- W-scan: thread c (<64) serial over 128 px; banks 2-way -------
        if (t < 64) {
            float s = s_carry;
#pragma unroll 8
            for (int xi = 0; xi < 128; ++xi) {
                uint32_t pk = gv[xi * 65 + t];
                float g = __uint_as_float(pk << 16);
                float v = __uint_as_float(pk & 0xffff0000u);
                s = __builtin_fmaf(g, s, v);
                gv[xi * 65 + t] = __builtin_amdgcn_perm(__float_as_uint(s), pk, 0x07060100u);
            }
            s_carry = s;
        }
        __syncthreads();

        // ---- write packed (gate, hw), coalesced 256 B per wave ------------
#pragma unroll
        for (int i = 0; i < 32; ++i) {
            int idx = i * 256 + t;          // 0..8191
            int c = idx >> 7, px = idx & 127;
            pair[rowoff + (size_t)c * HWSZ + x0 + px] = gv[px * 65 + c];
        }
        __syncthreads();
    }
}

// ---------------- K3: H-scan + residual, prefetched, in-place on d_out -----
__global__ __launch_bounds__(256) void k_hscan(
        uint32_t* __restrict__ io, const float* __restrict__ x) {
    int t = threadIdx.x;
    size_t base = (size_t)blockIdx.x * HWSZ + t;
    uint32_t pk[16]; float xv[16];
#pragma unroll
    for (int j = 0; j < 16; ++j) pk[j] = io[base + (size_t)j * WW];
#pragma unroll
    for (int j = 0; j < 16; ++j) xv[j] = x[base + (size_t)j * WW];
    float s = 0.f;
    for (int yt = 0; yt < 16; ++yt) {
        uint32_t npk[16]; float nxv[16];
        if (yt < 15) {                       // prefetch next 16-row group
            size_t nb = base + (size_t)(yt + 1) * 16 * WW;
#pragma unroll
            for (int j = 0; j < 16; ++j) npk[j] = io[nb + (size_t)j * WW];
#pragma unroll
            for (int j = 0; j < 16; ++j) nxv[j] = x[nb + (size_t)j * WW];
        }
        float gj[16], vj[16];                // hoist unpack out of serial chain
#pragma unroll
        for (int j = 0; j < 16; ++j) {
            float g   = __uint_as_float(pk[j] << 16);
            float hwv = __uint_as_float(pk[j] & 0xffff0000u);
            gj[j] = g; vj[j] = (1.f - g) * hwv;
        }
        float res[16];
#pragma unroll
        for (int j = 0; j < 16; ++j) { s = __builtin_fmaf(gj[j], s, vj[j]); res[j] = xv[j] + s; }
        size_t ob = base + (size_t)yt * 16 * WW;
#pragma unroll
        for (int j = 0; j < 16; ++j) io[ob + (size_t)j * WW] = __float_as_uint(res[j]);
#pragma unroll
        for (int j = 0; j < 16; ++j) { pk[j] = npk[j]; xv[j] = nxv[j]; }
    }
}

extern "C" void kernel_launch(void* const* d_in, const int* in_sizes, int n_in,
                              void* d_out, int out_size, void* d_ws, size_t ws_size,
                              hipStream_t stream) {
    const float* x      = (const float*)d_in[0];
    const float* gn_w   = (const float*)d_in[1];
    const float* gn_b   = (const float*)d_in[2];
    const float* gate_w = (const float*)d_in[3];
    const float* gate_b = (const float*)d_in[4];
    const float* upd_w  = (const float*)d_in[5];
    const float* upd_b  = (const float*)d_in[6];

    char* ws = (char*)d_ws;
    float2*   part  = (float2*)(ws + WS_PART_OFF);
    float2*   aff   = (float2*)(ws + WS_AFF_OFF);
    uint32_t* wfrag = (uint32_t*)(ws + WS_WFRAG_OFF);
    uint32_t* pair  = (uint32_t*)d_out;   // packed (gate,hw); K3 rewrites in place

    k_wfrag<<<16, 256, 0, stream>>>(gate_w, upd_w, wfrag);
    k_stats_partial<<<512, 256, 0, stream>>>(x, part);
    k_stats_final<<<1, 512, 0, stream>>>(part, gn_w, gn_b, aff);
    k_row<<<BB * HH, 256, 0, stream>>>(x, wfrag, gate_b, upd_b, aff, pair);
    k_hscan<<<BB * CC, 256, 0, stream>>>(pair, x);
}